// Round 6
// baseline (1190.132 us; speedup 1.0000x reference)
//
#include <hip/hip_runtime.h>

#pragma clang fp contract(off)

#define NPT 4096
#define B_ 16
#define S_ 1024
#define K_ 32
#define ROWS (B_*S_*K_)   // 524288
#define PNB 1024          // partial-stats blocks (layer kernels' grid)

typedef float v2f __attribute__((ext_vector_type(2)));
typedef unsigned int u32;
typedef unsigned long long u64;
typedef __attribute__((ext_vector_type(8))) short s16x8;
typedef __attribute__((ext_vector_type(4))) float f32x4;
typedef __attribute__((ext_vector_type(8))) unsigned short us8v;

// float readlane broadcast (SALU v_readlane -> scalar operand)
__device__ __forceinline__ float rlf(float v, int l) {
  return __uint_as_float(__builtin_amdgcn_readlane(__float_as_uint(v), l));
}

__device__ __forceinline__ short rne_bf16(float x) {
  u32 b = __float_as_uint(x);
  b += 0x7FFFu + ((b >> 16) & 1u);
  return (short)(b >> 16);
}
__device__ __forceinline__ float bf16_to_f(unsigned short h) {
  return __uint_as_float(((u32)h) << 16);
}

__device__ __forceinline__ f32x4 mfma16(s16x8 a, s16x8 b, f32x4 c) {
  return __builtin_amdgcn_mfma_f32_16x16x32_bf16(a, b, c, 0, 0, 0);
}

template <int CTRL>
__device__ __forceinline__ float dpp_f32(float x) {
  int r = __builtin_amdgcn_update_dpp(__float_as_int(x), __float_as_int(x), CTRL, 0xF, 0xF, false);
  return __int_as_float(r);
}
// full-wave f32 max -> lane 63 (VOP2 v_max_f32 with DPP modifier, no reg-pair moves)
__device__ __forceinline__ float wave_max_f32(float k) {
  k = fmaxf(k, dpp_f32<0x111>(k));  // row_shr:1
  k = fmaxf(k, dpp_f32<0x112>(k));  // row_shr:2
  k = fmaxf(k, dpp_f32<0x114>(k));  // row_shr:4
  k = fmaxf(k, dpp_f32<0x118>(k));  // row_shr:8
  k = fmaxf(k, dpp_f32<0x142>(k));  // row_bcast:15
  k = fmaxf(k, dpp_f32<0x143>(k));  // row_bcast:31
  return k;
}

// ---------------- FPS: one block per batch, 256 threads, 16 pts/thread ----------------
__global__ __launch_bounds__(256) void fps_kernel(const float* __restrict__ xyz,
    float* __restrict__ out0, float* __restrict__ new_xyz) {
  const int b = blockIdx.x, t = threadIdx.x;
  const float* xb = xyz + (size_t)b * 3 * NPT;
  __shared__ float4 spt[NPT];       // 64 KB: (x,y,z,-)
  __shared__ u64 skey[3];           // 3-slot rotating argmax cell
  __shared__ int sfar[S_];          // selected index per iteration
  // coalesced stage into LDS
#pragma unroll
  for (int j = 0; j < 16; j++) {
    int m = t + j * 256;
    spt[m] = make_float4(xb[m], xb[NPT + m], xb[2 * NPT + m], 0.f);
  }
  if (t < 3) skey[t] = 0ull;
  // lane-local consecutive points n = t*16+i, loaded from global (coalesced float4)
  const float4* xb4 = (const float4*)xb;
  v2f px[8], py[8], pz[8], ds[8];
#pragma unroll
  for (int q = 0; q < 4; q++) {
    float4 X = xb4[t * 4 + q];
    float4 Y = xb4[NPT / 4 + t * 4 + q];
    float4 Z = xb4[2 * NPT / 4 + t * 4 + q];
    px[2 * q] = (v2f){X.x, X.y}; px[2 * q + 1] = (v2f){X.z, X.w};
    py[2 * q] = (v2f){Y.x, Y.y}; py[2 * q + 1] = (v2f){Y.z, Y.w};
    pz[2 * q] = (v2f){Z.x, Z.y}; pz[2 * q + 1] = (v2f){Z.z, Z.w};
  }
#pragma unroll
  for (int j = 0; j < 8; j++) ds[j] = (v2f){1e10f, 1e10f};
  __syncthreads();
  int far = 0, slot = 0;
  const int base = t * 16;
  for (int it = 0; it < S_; ++it) {
    if (t == 0) sfar[it] = far;
    float4 c = spt[far];
    v2f cx = (v2f){c.x, c.x}, cy = (v2f){c.y, c.y}, cz = (v2f){c.z, c.z};
#pragma unroll
    for (int j = 0; j < 8; j++) {
      // exact ref op order per element: ((dx*dx + dy*dy) + dz*dz), contraction OFF
      v2f dx = px[j] - cx, dy = py[j] - cy, dz = pz[j] - cz;
      v2f s = dx * dx + dy * dy;
      v2f d = s + dz * dz;
      ds[j] = __builtin_elementwise_min(ds[j], d);
    }
    // per-lane max (packed tree), then wave max (f32 DPP)
    v2f m0 = __builtin_elementwise_max(ds[0], ds[1]);
    v2f m1 = __builtin_elementwise_max(ds[2], ds[3]);
    v2f m2 = __builtin_elementwise_max(ds[4], ds[5]);
    v2f m3 = __builtin_elementwise_max(ds[6], ds[7]);
    m0 = __builtin_elementwise_max(m0, m1);
    m2 = __builtin_elementwise_max(m2, m3);
    m0 = __builtin_elementwise_max(m0, m2);
    float bv = fmaxf(m0.x, m0.y);
    float wmax = rlf(wave_max_f32(bv), 63);
    if (bv == wmax) {                 // ~1 lane per wave: resolve min local idx, contribute key
      int idx = 0;
#pragma unroll
      for (int i = 15; i >= 0; --i) {
        float v = (i & 1) ? ds[i >> 1].y : ds[i >> 1].x;
        if (v == wmax) idx = i;
      }
      u64 key = ((u64)__float_as_uint(wmax) << 32) | (u32)~(u32)(base + idx);
      atomicMax(&skey[slot], key);    // min global index wins via ~idx
    }
    __syncthreads();
    u64 kk = skey[slot];
    if (t == 0) skey[slot == 0 ? 2 : slot - 1] = 0ull;  // reset slot (it+2)%3: safe post-barrier
    far = (int)(~(u32)kk);
    slot = (slot == 2) ? 0 : slot + 1;
  }
  __syncthreads();
  // coalesced writeback of centroids
#pragma unroll
  for (int j = 0; j < 4; j++) {
    int it = t + j * 256;
    float4 p = spt[sfar[it]];
    out0[(b * 3 + 0) * S_ + it] = p.x;
    out0[(b * 3 + 1) * S_ + it] = p.y;
    out0[(b * 3 + 2) * S_ + it] = p.z;
    float* nz = new_xyz + ((size_t)b * S_ + it) * 3;
    nz[0] = p.x; nz[1] = p.y; nz[2] = p.z;
  }
}

// ---------------- Ball query: one wave per query ----------------
__global__ __launch_bounds__(256) void ballq_kernel(const float* __restrict__ xyz,
    const float* __restrict__ new_xyz, int* __restrict__ gidx) {
  const int wid = (blockIdx.x * 256 + threadIdx.x) >> 6;   // 16384 queries
  const int lane = threadIdx.x & 63;
  const int b = wid >> 10;
  const float* xb = xyz + (size_t)b * 3 * NPT;
  const float qx = new_xyz[(size_t)wid * 3 + 0];
  const float qy = new_xyz[(size_t)wid * 3 + 1];
  const float qz = new_xyz[(size_t)wid * 3 + 2];
  const float R2 = (float)(0.4 * 0.4);
  int* g = gidx + (size_t)wid * K_;
  int cnt = 0, firstIdx = 0x7fffffff;
  for (int c0 = 0; c0 < NPT && cnt < K_; c0 += 64) {
    int n = c0 + lane;
    float dx = __fadd_rn(qx, -xb[n]);
    float dy = __fadd_rn(qy, -xb[NPT + n]);
    float dz = __fadd_rn(qz, -xb[2 * NPT + n]);
    float sq = __fadd_rn(__fadd_rn(__fmul_rn(dx, dx), __fmul_rn(dy, dy)), __fmul_rn(dz, dz));
    bool inr = !(sq > R2);
    unsigned long long m = __ballot(inr);
    if (inr) {
      int pos = cnt + (int)__popcll(m & ((1ull << lane) - 1ull));
      if (pos < K_) g[pos] = n;
    }
    if (firstIdx == 0x7fffffff && m) firstIdx = c0 + (int)__builtin_ctzll(m);
    cnt += (int)__popcll(m);
  }
  if (lane >= cnt && lane < K_) g[lane] = firstIdx;  // pad with first (always exists: self)
}

// ---------------- Layer 1: gather+concat fused, 6->64, bf16 out + partial stats ----------------
__global__ __launch_bounds__(256) void layer1_kernel(
    const float* __restrict__ xyz, const float* __restrict__ pts,
    const float* __restrict__ new_xyz, const int* __restrict__ gidx,
    const float* __restrict__ W1, const float* __restrict__ b1,
    unsigned short* __restrict__ y1, float* __restrict__ partials) {
  __shared__ float sp[4 * 2 * 64];
  const int lane = threadIdx.x & 63, wv = threadIdx.x >> 6;
  const int nw = gridDim.x * 4;
  float w[6];
#pragma unroll
  for (int c = 0; c < 6; c++) w[c] = W1[lane * 6 + c];
  const float bias = b1[lane];
  float s0 = 0.f, s1 = 0.f;
  for (int r = blockIdx.x * 4 + wv; r < ROWS; r += nw) {
    int gi = gidx[r];
    int bs = r >> 5, b = bs >> 10;
    float v = 0.f;
    if (lane < 3)      v = xyz[((size_t)b * 3 + lane) * NPT + gi] - new_xyz[(size_t)bs * 3 + lane];
    else if (lane < 6) v = pts[((size_t)b * 3 + (lane - 3)) * NPT + gi];
    float acc = bias;
#pragma unroll
    for (int c = 0; c < 6; c++) acc = fmaf(rlf(v, c), w[c], acc);
    y1[(size_t)r * 64 + lane] = (unsigned short)rne_bf16(acc);
    s0 += acc; s1 = fmaf(acc, acc, s1);
  }
  sp[(wv * 2 + 0) * 64 + lane] = s0;
  sp[(wv * 2 + 1) * 64 + lane] = s1;
  __syncthreads();
  if (threadIdx.x < 128) {
    float p = sp[threadIdx.x] + sp[threadIdx.x + 128] + sp[threadIdx.x + 256] + sp[threadIdx.x + 384];
    partials[(size_t)threadIdx.x * PNB + blockIdx.x] = p;   // transposed: [stat_row][block]
  }
}

// ---------------- MFMA layer: bn(prev)+relu -> bf16 -> GEMM(64->NT*16) + stats ----------------
template <int NT, bool WRITE_OUT>
__global__ __launch_bounds__(256) void mfma_layer_kernel(
    const unsigned short* __restrict__ yin,   // [M][64] bf16 pre-BN
    const float* __restrict__ W,              // [NT*16][64] f32
    const float* __restrict__ bias,           // [NT*16]
    const float* __restrict__ bnin,           // scale[64], shift[64]
    unsigned short* __restrict__ yout,        // [M][NT*16] bf16 pre-BN (or unused)
    float* __restrict__ partials) {
  constexpr int COUT = NT * 16;
  const int lane = threadIdx.x & 63, wv = threadIdx.x >> 6;
  const int quad = lane >> 4, l16 = lane & 15;
  // loop-invariants: B-frags (W is [n][k] = exactly B-operand layout), bias, input BN
  s16x8 bfrag[NT][2];
  float biasr[NT];
#pragma unroll
  for (int t = 0; t < NT; t++) {
    int n = l16 + 16 * t;
    biasr[t] = bias[n];
#pragma unroll
    for (int kc = 0; kc < 2; kc++)
#pragma unroll
      for (int j = 0; j < 8; j++)
        bfrag[t][kc][j] = rne_bf16(W[(size_t)n * 64 + kc * 32 + quad * 8 + j]);
  }
  float isc[2][8], ish[2][8];
#pragma unroll
  for (int kc = 0; kc < 2; kc++)
#pragma unroll
    for (int j = 0; j < 8; j++) {
      int k = kc * 32 + quad * 8 + j;
      isc[kc][j] = bnin[k]; ish[kc][j] = bnin[64 + k];
    }
  float s0[NT], s1[NT];
#pragma unroll
  for (int t = 0; t < NT; t++) { s0[t] = 0.f; s1[t] = 0.f; }
  const int nwaves = gridDim.x * 4;
  for (int mt = blockIdx.x * 4 + wv; mt < ROWS / 16; mt += nwaves) {
    int row = mt * 16 + l16;
    const unsigned short* p = yin + (size_t)row * 64 + quad * 8;
    us8v r0 = *(const us8v*)p;
    us8v r1 = *(const us8v*)(p + 32);
    s16x8 a0, a1;
#pragma unroll
    for (int j = 0; j < 8; j++) {
      float z0 = fmaxf(fmaf(bf16_to_f(r0[j]), isc[0][j], ish[0][j]), 0.f);
      float z1 = fmaxf(fmaf(bf16_to_f(r1[j]), isc[1][j], ish[1][j]), 0.f);
      a0[j] = rne_bf16(z0); a1[j] = rne_bf16(z1);
    }
    f32x4 acc[NT];
#pragma unroll
    for (int t = 0; t < NT; t++) {
      acc[t] = (f32x4){biasr[t], biasr[t], biasr[t], biasr[t]};
      acc[t] = mfma16(a0, bfrag[t][0], acc[t]);
      acc[t] = mfma16(a1, bfrag[t][1], acc[t]);
    }
#pragma unroll
    for (int t = 0; t < NT; t++) {
#pragma unroll
      for (int r = 0; r < 4; r++) {
        float v = acc[t][r];                       // D[row=quad*4+r][col=l16+16t]
        s0[t] += v; s1[t] = fmaf(v, v, s1[t]);
        if (WRITE_OUT) {
          int m = mt * 16 + quad * 4 + r;
          yout[(size_t)m * COUT + l16 + 16 * t] = (unsigned short)rne_bf16(v);
        }
      }
    }
  }
  // reduce stats: lanes {n, n+16, n+32, n+48} hold the same channel
#pragma unroll
  for (int t = 0; t < NT; t++) {
    s0[t] += __shfl_xor(s0[t], 16); s0[t] += __shfl_xor(s0[t], 32);
    s1[t] += __shfl_xor(s1[t], 16); s1[t] += __shfl_xor(s1[t], 32);
  }
  __shared__ float sp[4 * 2 * COUT];
  if (quad == 0) {
#pragma unroll
    for (int t = 0; t < NT; t++) {
      sp[wv * 2 * COUT + l16 + 16 * t] = s0[t];
      sp[wv * 2 * COUT + COUT + l16 + 16 * t] = s1[t];
    }
  }
  __syncthreads();
  for (int tt = threadIdx.x; tt < 2 * COUT; tt += 256) {
    float p = sp[tt] + sp[2 * COUT + tt] + sp[4 * COUT + tt] + sp[6 * COUT + tt];
    partials[(size_t)tt * PNB + blockIdx.x] = p;
  }
}

// ---------------- fold partials -> bn scale/shift (one block per channel) ----------------
__global__ __launch_bounds__(256) void finalize_kernel(const float* __restrict__ partials,
    int cout, const float* __restrict__ g, const float* __restrict__ be,
    float* __restrict__ bn) {
  const int c = blockIdx.x;
  const int t = threadIdx.x;
  const int lane = t & 63, wv = t >> 6;
  float s0 = 0.f, s1 = 0.f;
  for (int bb = t; bb < PNB; bb += 256) {
    s0 += partials[(size_t)c * PNB + bb];
    s1 += partials[(size_t)(cout + c) * PNB + bb];
  }
#pragma unroll
  for (int off = 32; off; off >>= 1) {
    s0 += __shfl_xor(s0, off);
    s1 += __shfl_xor(s1, off);
  }
  __shared__ float r0[4], r1[4];
  if (lane == 0) { r0[wv] = s0; r1[wv] = s1; }
  __syncthreads();
  if (t == 0) {
    double d0 = (double)r0[0] + r0[1] + r0[2] + r0[3];
    double d1 = (double)r1[0] + r1[1] + r1[2] + r1[3];
    double N = (double)ROWS;
    double mean = d0 / N;
    double var = d1 / N - mean * mean;
    double scale = (double)g[c] / sqrt(var + 1e-5);
    bn[c] = (float)scale;
    bn[cout + c] = (float)((double)be[c] - mean * scale);
  }
}

// ---------------- Layer3 recompute (MFMA) + bn3 + relu + max over K + transposed store ----------------
__global__ __launch_bounds__(256) void l3max_kernel(
    const unsigned short* __restrict__ y2, const float* __restrict__ W3,
    const float* __restrict__ b3, const float* __restrict__ bn2,
    const float* __restrict__ bn3, float* __restrict__ out1) {
  constexpr int NT = 8;
  const int lane = threadIdx.x & 63, wv = threadIdx.x >> 6;
  const int quad = lane >> 4, l16 = lane & 15;
  const int gq = blockIdx.x * 4 + wv;            // 16384 (b,s) groups
  s16x8 bfrag[NT][2];
  float biasr[NT], s3[NT], h3[NT];
#pragma unroll
  for (int t = 0; t < NT; t++) {
    int n = l16 + 16 * t;
    biasr[t] = b3[n]; s3[t] = bn3[n]; h3[t] = bn3[128 + n];
#pragma unroll
    for (int kc = 0; kc < 2; kc++)
#pragma unroll
      for (int j = 0; j < 8; j++)
        bfrag[t][kc][j] = rne_bf16(W3[(size_t)n * 64 + kc * 32 + quad * 8 + j]);
  }
  float isc[2][8], ish[2][8];
#pragma unroll
  for (int kc = 0; kc < 2; kc++)
#pragma unroll
    for (int j = 0; j < 8; j++) {
      int k = kc * 32 + quad * 8 + j;
      isc[kc][j] = bn2[k]; ish[kc][j] = bn2[64 + k];
    }
  float mx[NT];
#pragma unroll
  for (int t = 0; t < NT; t++) mx[t] = -1e30f;
#pragma unroll
  for (int mt2 = 0; mt2 < 2; mt2++) {            // 32 rows = 2 M-tiles
    int row = gq * 32 + mt2 * 16 + l16;
    const unsigned short* p = y2 + (size_t)row * 64 + quad * 8;
    us8v r0 = *(const us8v*)p;
    us8v r1 = *(const us8v*)(p + 32);
    s16x8 a0, a1;
#pragma unroll
    for (int j = 0; j < 8; j++) {
      float z0 = fmaxf(fmaf(bf16_to_f(r0[j]), isc[0][j], ish[0][j]), 0.f);
      float z1 = fmaxf(fmaf(bf16_to_f(r1[j]), isc[1][j], ish[1][j]), 0.f);
      a0[j] = rne_bf16(z0); a1[j] = rne_bf16(z1);
    }
#pragma unroll
    for (int t = 0; t < NT; t++) {
      f32x4 acc = (f32x4){biasr[t], biasr[t], biasr[t], biasr[t]};
      acc = mfma16(a0, bfrag[t][0], acc);
      acc = mfma16(a1, bfrag[t][1], acc);
#pragma unroll
      for (int r = 0; r < 4; r++) {
        float z = fmaxf(fmaf(acc[r], s3[t], h3[t]), 0.f);
        mx[t] = fmaxf(mx[t], z);
      }
    }
  }
#pragma unroll
  for (int t = 0; t < NT; t++) {
    mx[t] = fmaxf(mx[t], __shfl_xor(mx[t], 16));
    mx[t] = fmaxf(mx[t], __shfl_xor(mx[t], 32));
  }
  __shared__ float tile[128 * 4];   // [ch][s_local]
  if (quad == 0) {
#pragma unroll
    for (int t = 0; t < NT; t++) tile[(l16 + 16 * t) * 4 + wv] = mx[t];
  }
  __syncthreads();
  if (threadIdx.x < 128) {
    int b = blockIdx.x >> 8;            // 256 blocks per batch
    int s0i = (blockIdx.x & 255) * 4;
    float4 vv = *(float4*)&tile[threadIdx.x * 4];
    *(float4*)&out1[((size_t)b * 128 + threadIdx.x) * 1024 + s0i] = vv;
  }
}

extern "C" void kernel_launch(void* const* d_in, const int* in_sizes, int n_in,
                              void* d_out, int out_size, void* d_ws, size_t ws_size,
                              hipStream_t stream) {
  const float* xyz = (const float*)d_in[0];
  const float* pts = (const float*)d_in[1];
  const float* W1 = (const float*)d_in[2],  *b1 = (const float*)d_in[3];
  const float* g1 = (const float*)d_in[4],  *be1 = (const float*)d_in[5];
  const float* W2 = (const float*)d_in[6],  *b2 = (const float*)d_in[7];
  const float* g2 = (const float*)d_in[8],  *be2 = (const float*)d_in[9];
  const float* W3 = (const float*)d_in[10], *b3 = (const float*)d_in[11];
  const float* g3 = (const float*)d_in[12], *be3 = (const float*)d_in[13];
  float* out0 = (float*)d_out;                 // xyz_query_pc [16,3,1024]
  float* out1 = out0 + B_ * 3 * S_;            // new_points   [16,128,1024]

  char* ws = (char*)d_ws;
  float* new_xyz  = (float*)(ws);              // 49152 floats
  float* bn1      = (float*)(ws + 196608);     // 128
  float* bn2      = bn1 + 128;                 // 128
  float* bn3      = bn2 + 128;                 // 256
  int*   gidx     = (int*)(ws + 198656);       // 524288 ints
  float* partials = (float*)(ws + 2295808);    // 256*PNB floats (1 MB)
  unsigned short* y1 = (unsigned short*)(ws + 4392960);           // 64 MB bf16
  unsigned short* y2 = (unsigned short*)(ws + 4392960 + 67108864); // 64 MB bf16

  fps_kernel<<<B_, 256, 0, stream>>>(xyz, out0, new_xyz);
  ballq_kernel<<<4096, 256, 0, stream>>>(xyz, new_xyz, gidx);
  layer1_kernel<<<PNB, 256, 0, stream>>>(xyz, pts, new_xyz, gidx, W1, b1, y1, partials);
  finalize_kernel<<<64, 256, 0, stream>>>(partials, 64, g1, be1, bn1);
  mfma_layer_kernel<4, true><<<PNB, 256, 0, stream>>>(y1, W2, b2, bn1, y2, partials);
  finalize_kernel<<<64, 256, 0, stream>>>(partials, 64, g2, be2, bn2);
  mfma_layer_kernel<8, false><<<PNB, 256, 0, stream>>>(y2, W3, b3, bn2, nullptr, partials);
  finalize_kernel<<<128, 256, 0, stream>>>(partials, 128, g3, be3, bn3);
  l3max_kernel<<<4096, 256, 0, stream>>>(y2, W3, b3, bn2, bn3, out1);
}

// Round 7
// 1074.139 us; speedup vs baseline: 1.1080x; 1.1080x over previous
//
#include <hip/hip_runtime.h>

#pragma clang fp contract(off)

#define NPT 4096
#define B_ 16
#define S_ 1024
#define K_ 32
#define ROWS (B_*S_*K_)   // 524288
#define PNB 1024          // partial-stats blocks (layer kernels' grid)

typedef float v2f __attribute__((ext_vector_type(2)));
typedef unsigned int u32;
typedef unsigned long long u64;
typedef __attribute__((ext_vector_type(8))) short s16x8;
typedef __attribute__((ext_vector_type(4))) float f32x4;
typedef __attribute__((ext_vector_type(8))) unsigned short us8v;

// float readlane broadcast (SALU v_readlane -> scalar operand)
__device__ __forceinline__ float rlf(float v, int l) {
  return __uint_as_float(__builtin_amdgcn_readlane(__float_as_uint(v), l));
}

__device__ __forceinline__ short rne_bf16(float x) {
  u32 b = __float_as_uint(x);
  b += 0x7FFFu + ((b >> 16) & 1u);
  return (short)(b >> 16);
}
__device__ __forceinline__ float bf16_to_f(unsigned short h) {
  return __uint_as_float(((u32)h) << 16);
}

__device__ __forceinline__ f32x4 mfma16(s16x8 a, s16x8 b, f32x4 c) {
  return __builtin_amdgcn_mfma_f32_16x16x32_bf16(a, b, c, 0, 0, 0);
}

template <int CTRL>
__device__ __forceinline__ float dpp_f32(float x) {
  int r = __builtin_amdgcn_update_dpp(__float_as_int(x), __float_as_int(x), CTRL, 0xF, 0xF, false);
  return __int_as_float(r);
}
// full-wave f32 max -> lane 63 (VOP2 v_max_f32 with DPP modifier, no reg-pair moves)
__device__ __forceinline__ float wave_max_f32(float k) {
  k = fmaxf(k, dpp_f32<0x111>(k));  // row_shr:1
  k = fmaxf(k, dpp_f32<0x112>(k));  // row_shr:2
  k = fmaxf(k, dpp_f32<0x114>(k));  // row_shr:4
  k = fmaxf(k, dpp_f32<0x118>(k));  // row_shr:8
  k = fmaxf(k, dpp_f32<0x142>(k));  // row_bcast:15
  k = fmaxf(k, dpp_f32<0x143>(k));  // row_bcast:31
  return k;
}

// ---------------- FPS: one block per batch, 512 threads, 8 pts/thread ----------------
// 512 threads => 8 waves = 2 waves/SIMD (latency overlap) + short per-wave issue count.
__global__ __launch_bounds__(512) void fps_kernel(const float* __restrict__ xyz,
    float* __restrict__ out0, float* __restrict__ new_xyz) {
  const int b = blockIdx.x, t = threadIdx.x;
  const int lane = t & 63;
  const float* xb = xyz + (size_t)b * 3 * NPT;
  __shared__ float4 spt[NPT];       // 64 KB: (x,y,z,-) for centroid broadcast
  __shared__ u64 skey[3];           // 3-slot rotating argmax cell
  __shared__ int sfar[S_];          // selected index per iteration
  // coalesced stage into LDS
#pragma unroll
  for (int j = 0; j < 8; j++) {
    int m = t + j * 512;
    spt[m] = make_float4(xb[m], xb[NPT + m], xb[2 * NPT + m], 0.f);
  }
  if (t < 3) skey[t] = 0ull;
  // lane-local consecutive points n = t*8+i, loaded from global (coalesced float4)
  const float4* xb4 = (const float4*)xb;
  float4 X0 = xb4[t * 2], X1 = xb4[t * 2 + 1];
  float4 Y0 = xb4[NPT / 4 + t * 2], Y1 = xb4[NPT / 4 + t * 2 + 1];
  float4 Z0 = xb4[2 * NPT / 4 + t * 2], Z1 = xb4[2 * NPT / 4 + t * 2 + 1];
  v2f px[4], py[4], pz[4], ds[4];
  px[0] = (v2f){X0.x, X0.y}; px[1] = (v2f){X0.z, X0.w}; px[2] = (v2f){X1.x, X1.y}; px[3] = (v2f){X1.z, X1.w};
  py[0] = (v2f){Y0.x, Y0.y}; py[1] = (v2f){Y0.z, Y0.w}; py[2] = (v2f){Y1.x, Y1.y}; py[3] = (v2f){Y1.z, Y1.w};
  pz[0] = (v2f){Z0.x, Z0.y}; pz[1] = (v2f){Z0.z, Z0.w}; pz[2] = (v2f){Z1.x, Z1.y}; pz[3] = (v2f){Z1.z, Z1.w};
#pragma unroll
  for (int j = 0; j < 4; j++) ds[j] = (v2f){1e10f, 1e10f};
  __syncthreads();
  int far = 0, slot = 0;
  const int base = t * 8;
  for (int it = 0; it < S_; ++it) {
    if (t == 0) sfar[it] = far;
    float4 c = spt[far];
    v2f cx = (v2f){c.x, c.x}, cy = (v2f){c.y, c.y}, cz = (v2f){c.z, c.z};
#pragma unroll
    for (int j = 0; j < 4; j++) {
      // exact ref op order per element: ((dx*dx + dy*dy) + dz*dz), contraction OFF
      v2f dx = px[j] - cx, dy = py[j] - cy, dz = pz[j] - cz;
      v2f s = dx * dx + dy * dy;
      v2f d = s + dz * dz;
      ds[j] = __builtin_elementwise_min(ds[j], d);
    }
    // per-lane max (packed tree), then wave max (f32 DPP)
    v2f m0 = __builtin_elementwise_max(ds[0], ds[1]);
    v2f m1 = __builtin_elementwise_max(ds[2], ds[3]);
    m0 = __builtin_elementwise_max(m0, m1);
    float bv = fmaxf(m0.x, m0.y);
    float wmax = rlf(wave_max_f32(bv), 63);
    if (bv == wmax) {                 // ~1 lane per wave: resolve min local idx, contribute key
      int idx = 0;
#pragma unroll
      for (int i = 7; i >= 0; --i) {
        float v = (i & 1) ? ds[i >> 1].y : ds[i >> 1].x;
        if (v == wmax) idx = i;
      }
      u64 key = ((u64)__float_as_uint(wmax) << 32) | (u32)~(u32)(base + idx);
      atomicMax(&skey[slot], key);    // min global index wins via ~idx
    }
    __syncthreads();
    u64 kk = skey[slot];
    if (t == 0) skey[slot == 0 ? 2 : slot - 1] = 0ull;  // reset slot (it+2)%3: safe post-barrier
    far = (int)(~(u32)kk);
    slot = (slot == 2) ? 0 : slot + 1;
  }
  __syncthreads();
  // coalesced writeback of centroids
#pragma unroll
  for (int j = 0; j < 2; j++) {
    int it = t + j * 512;
    float4 p = spt[sfar[it]];
    out0[(b * 3 + 0) * S_ + it] = p.x;
    out0[(b * 3 + 1) * S_ + it] = p.y;
    out0[(b * 3 + 2) * S_ + it] = p.z;
    float* nz = new_xyz + ((size_t)b * S_ + it) * 3;
    nz[0] = p.x; nz[1] = p.y; nz[2] = p.z;
  }
}

// ---------------- Ball query: one wave per query ----------------
__global__ __launch_bounds__(256) void ballq_kernel(const float* __restrict__ xyz,
    const float* __restrict__ new_xyz, int* __restrict__ gidx) {
  const int wid = (blockIdx.x * 256 + threadIdx.x) >> 6;   // 16384 queries
  const int lane = threadIdx.x & 63;
  const int b = wid >> 10;
  const float* xb = xyz + (size_t)b * 3 * NPT;
  const float qx = new_xyz[(size_t)wid * 3 + 0];
  const float qy = new_xyz[(size_t)wid * 3 + 1];
  const float qz = new_xyz[(size_t)wid * 3 + 2];
  const float R2 = (float)(0.4 * 0.4);
  int* g = gidx + (size_t)wid * K_;
  int cnt = 0, firstIdx = 0x7fffffff;
  for (int c0 = 0; c0 < NPT && cnt < K_; c0 += 64) {
    int n = c0 + lane;
    float dx = __fadd_rn(qx, -xb[n]);
    float dy = __fadd_rn(qy, -xb[NPT + n]);
    float dz = __fadd_rn(qz, -xb[2 * NPT + n]);
    float sq = __fadd_rn(__fadd_rn(__fmul_rn(dx, dx), __fmul_rn(dy, dy)), __fmul_rn(dz, dz));
    bool inr = !(sq > R2);
    unsigned long long m = __ballot(inr);
    if (inr) {
      int pos = cnt + (int)__popcll(m & ((1ull << lane) - 1ull));
      if (pos < K_) g[pos] = n;
    }
    if (firstIdx == 0x7fffffff && m) firstIdx = c0 + (int)__builtin_ctzll(m);
    cnt += (int)__popcll(m);
  }
  if (lane >= cnt && lane < K_) g[lane] = firstIdx;  // pad with first (always exists: self)
}

// ---------------- Layer 1: gather+concat fused, 6->64, bf16 out + partial stats ----------------
__global__ __launch_bounds__(256) void layer1_kernel(
    const float* __restrict__ xyz, const float* __restrict__ pts,
    const float* __restrict__ new_xyz, const int* __restrict__ gidx,
    const float* __restrict__ W1, const float* __restrict__ b1,
    unsigned short* __restrict__ y1, float* __restrict__ partials) {
  __shared__ float sp[4 * 2 * 64];
  const int lane = threadIdx.x & 63, wv = threadIdx.x >> 6;
  const int nw = gridDim.x * 4;
  float w[6];
#pragma unroll
  for (int c = 0; c < 6; c++) w[c] = W1[lane * 6 + c];
  const float bias = b1[lane];
  float s0 = 0.f, s1 = 0.f;
  for (int r = blockIdx.x * 4 + wv; r < ROWS; r += nw) {
    int gi = gidx[r];
    int bs = r >> 5, b = bs >> 10;
    float v = 0.f;
    if (lane < 3)      v = xyz[((size_t)b * 3 + lane) * NPT + gi] - new_xyz[(size_t)bs * 3 + lane];
    else if (lane < 6) v = pts[((size_t)b * 3 + (lane - 3)) * NPT + gi];
    float acc = bias;
#pragma unroll
    for (int c = 0; c < 6; c++) acc = fmaf(rlf(v, c), w[c], acc);
    y1[(size_t)r * 64 + lane] = (unsigned short)rne_bf16(acc);
    s0 += acc; s1 = fmaf(acc, acc, s1);
  }
  sp[(wv * 2 + 0) * 64 + lane] = s0;
  sp[(wv * 2 + 1) * 64 + lane] = s1;
  __syncthreads();
  if (threadIdx.x < 128) {
    float p = sp[threadIdx.x] + sp[threadIdx.x + 128] + sp[threadIdx.x + 256] + sp[threadIdx.x + 384];
    partials[(size_t)threadIdx.x * PNB + blockIdx.x] = p;   // transposed: [stat_row][block]
  }
}

// ---------------- MFMA layer: bn(prev)+relu -> bf16 -> GEMM(64->NT*16) + stats ----------------
template <int NT, bool WRITE_OUT>
__global__ __launch_bounds__(256) void mfma_layer_kernel(
    const unsigned short* __restrict__ yin,   // [M][64] bf16 pre-BN
    const float* __restrict__ W,              // [NT*16][64] f32
    const float* __restrict__ bias,           // [NT*16]
    const float* __restrict__ bnin,           // scale[64], shift[64]
    unsigned short* __restrict__ yout,        // [M][NT*16] bf16 pre-BN (or unused)
    float* __restrict__ partials) {
  constexpr int COUT = NT * 16;
  const int lane = threadIdx.x & 63, wv = threadIdx.x >> 6;
  const int quad = lane >> 4, l16 = lane & 15;
  // loop-invariants: B-frags (W is [n][k] = exactly B-operand layout), bias, input BN
  s16x8 bfrag[NT][2];
  float biasr[NT];
#pragma unroll
  for (int t = 0; t < NT; t++) {
    int n = l16 + 16 * t;
    biasr[t] = bias[n];
#pragma unroll
    for (int kc = 0; kc < 2; kc++)
#pragma unroll
      for (int j = 0; j < 8; j++)
        bfrag[t][kc][j] = rne_bf16(W[(size_t)n * 64 + kc * 32 + quad * 8 + j]);
  }
  float isc[2][8], ish[2][8];
#pragma unroll
  for (int kc = 0; kc < 2; kc++)
#pragma unroll
    for (int j = 0; j < 8; j++) {
      int k = kc * 32 + quad * 8 + j;
      isc[kc][j] = bnin[k]; ish[kc][j] = bnin[64 + k];
    }
  float s0[NT], s1[NT];
#pragma unroll
  for (int t = 0; t < NT; t++) { s0[t] = 0.f; s1[t] = 0.f; }
  const int nwaves = gridDim.x * 4;
  for (int mt = blockIdx.x * 4 + wv; mt < ROWS / 16; mt += nwaves) {
    int row = mt * 16 + l16;
    const unsigned short* p = yin + (size_t)row * 64 + quad * 8;
    us8v r0 = *(const us8v*)p;
    us8v r1 = *(const us8v*)(p + 32);
    s16x8 a0, a1;
#pragma unroll
    for (int j = 0; j < 8; j++) {
      float z0 = fmaxf(fmaf(bf16_to_f(r0[j]), isc[0][j], ish[0][j]), 0.f);
      float z1 = fmaxf(fmaf(bf16_to_f(r1[j]), isc[1][j], ish[1][j]), 0.f);
      a0[j] = rne_bf16(z0); a1[j] = rne_bf16(z1);
    }
    f32x4 acc[NT];
#pragma unroll
    for (int t = 0; t < NT; t++) {
      acc[t] = (f32x4){biasr[t], biasr[t], biasr[t], biasr[t]};
      acc[t] = mfma16(a0, bfrag[t][0], acc[t]);
      acc[t] = mfma16(a1, bfrag[t][1], acc[t]);
    }
#pragma unroll
    for (int t = 0; t < NT; t++) {
#pragma unroll
      for (int r = 0; r < 4; r++) {
        float v = acc[t][r];                       // D[row=quad*4+r][col=l16+16t]
        s0[t] += v; s1[t] = fmaf(v, v, s1[t]);
        if (WRITE_OUT) {
          int m = mt * 16 + quad * 4 + r;
          yout[(size_t)m * COUT + l16 + 16 * t] = (unsigned short)rne_bf16(v);
        }
      }
    }
  }
  // reduce stats: lanes {n, n+16, n+32, n+48} hold the same channel
#pragma unroll
  for (int t = 0; t < NT; t++) {
    s0[t] += __shfl_xor(s0[t], 16); s0[t] += __shfl_xor(s0[t], 32);
    s1[t] += __shfl_xor(s1[t], 16); s1[t] += __shfl_xor(s1[t], 32);
  }
  __shared__ float sp[4 * 2 * COUT];
  if (quad == 0) {
#pragma unroll
    for (int t = 0; t < NT; t++) {
      sp[wv * 2 * COUT + l16 + 16 * t] = s0[t];
      sp[wv * 2 * COUT + COUT + l16 + 16 * t] = s1[t];
    }
  }
  __syncthreads();
  for (int tt = threadIdx.x; tt < 2 * COUT; tt += 256) {
    float p = sp[tt] + sp[2 * COUT + tt] + sp[4 * COUT + tt] + sp[6 * COUT + tt];
    partials[(size_t)tt * PNB + blockIdx.x] = p;
  }
}

// ---------------- fold partials -> bn scale/shift (one block per channel) ----------------
__global__ __launch_bounds__(256) void finalize_kernel(const float* __restrict__ partials,
    int cout, const float* __restrict__ g, const float* __restrict__ be,
    float* __restrict__ bn) {
  const int c = blockIdx.x;
  const int t = threadIdx.x;
  const int lane = t & 63, wv = t >> 6;
  float s0 = 0.f, s1 = 0.f;
  for (int bb = t; bb < PNB; bb += 256) {
    s0 += partials[(size_t)c * PNB + bb];
    s1 += partials[(size_t)(cout + c) * PNB + bb];
  }
#pragma unroll
  for (int off = 32; off; off >>= 1) {
    s0 += __shfl_xor(s0, off);
    s1 += __shfl_xor(s1, off);
  }
  __shared__ float r0[4], r1[4];
  if (lane == 0) { r0[wv] = s0; r1[wv] = s1; }
  __syncthreads();
  if (t == 0) {
    double d0 = (double)r0[0] + r0[1] + r0[2] + r0[3];
    double d1 = (double)r1[0] + r1[1] + r1[2] + r1[3];
    double N = (double)ROWS;
    double mean = d0 / N;
    double var = d1 / N - mean * mean;
    double scale = (double)g[c] / sqrt(var + 1e-5);
    bn[c] = (float)scale;
    bn[cout + c] = (float)((double)be[c] - mean * scale);
  }
}

// ---------------- Layer3 recompute (MFMA) + bn3 + relu + max over K + transposed store ----------------
__global__ __launch_bounds__(256) void l3max_kernel(
    const unsigned short* __restrict__ y2, const float* __restrict__ W3,
    const float* __restrict__ b3, const float* __restrict__ bn2,
    const float* __restrict__ bn3, float* __restrict__ out1) {
  constexpr int NT = 8;
  const int lane = threadIdx.x & 63, wv = threadIdx.x >> 6;
  const int quad = lane >> 4, l16 = lane & 15;
  const int gq = blockIdx.x * 4 + wv;            // 16384 (b,s) groups
  s16x8 bfrag[NT][2];
  float biasr[NT], s3[NT], h3[NT];
#pragma unroll
  for (int t = 0; t < NT; t++) {
    int n = l16 + 16 * t;
    biasr[t] = b3[n]; s3[t] = bn3[n]; h3[t] = bn3[128 + n];
#pragma unroll
    for (int kc = 0; kc < 2; kc++)
#pragma unroll
      for (int j = 0; j < 8; j++)
        bfrag[t][kc][j] = rne_bf16(W3[(size_t)n * 64 + kc * 32 + quad * 8 + j]);
  }
  float isc[2][8], ish[2][8];
#pragma unroll
  for (int kc = 0; kc < 2; kc++)
#pragma unroll
    for (int j = 0; j < 8; j++) {
      int k = kc * 32 + quad * 8 + j;
      isc[kc][j] = bn2[k]; ish[kc][j] = bn2[64 + k];
    }
  float mx[NT];
#pragma unroll
  for (int t = 0; t < NT; t++) mx[t] = -1e30f;
#pragma unroll
  for (int mt2 = 0; mt2 < 2; mt2++) {            // 32 rows = 2 M-tiles
    int row = gq * 32 + mt2 * 16 + l16;
    const unsigned short* p = y2 + (size_t)row * 64 + quad * 8;
    us8v r0 = *(const us8v*)p;
    us8v r1 = *(const us8v*)(p + 32);
    s16x8 a0, a1;
#pragma unroll
    for (int j = 0; j < 8; j++) {
      float z0 = fmaxf(fmaf(bf16_to_f(r0[j]), isc[0][j], ish[0][j]), 0.f);
      float z1 = fmaxf(fmaf(bf16_to_f(r1[j]), isc[1][j], ish[1][j]), 0.f);
      a0[j] = rne_bf16(z0); a1[j] = rne_bf16(z1);
    }
#pragma unroll
    for (int t = 0; t < NT; t++) {
      f32x4 acc = (f32x4){biasr[t], biasr[t], biasr[t], biasr[t]};
      acc = mfma16(a0, bfrag[t][0], acc);
      acc = mfma16(a1, bfrag[t][1], acc);
#pragma unroll
      for (int r = 0; r < 4; r++) {
        float z = fmaxf(fmaf(acc[r], s3[t], h3[t]), 0.f);
        mx[t] = fmaxf(mx[t], z);
      }
    }
  }
#pragma unroll
  for (int t = 0; t < NT; t++) {
    mx[t] = fmaxf(mx[t], __shfl_xor(mx[t], 16));
    mx[t] = fmaxf(mx[t], __shfl_xor(mx[t], 32));
  }
  __shared__ float tile[128 * 4];   // [ch][s_local]
  if (quad == 0) {
#pragma unroll
    for (int t = 0; t < NT; t++) tile[(l16 + 16 * t) * 4 + wv] = mx[t];
  }
  __syncthreads();
  if (threadIdx.x < 128) {
    int b = blockIdx.x >> 8;            // 256 blocks per batch
    int s0i = (blockIdx.x & 255) * 4;
    float4 vv = *(float4*)&tile[threadIdx.x * 4];
    *(float4*)&out1[((size_t)b * 128 + threadIdx.x) * 1024 + s0i] = vv;
  }
}

extern "C" void kernel_launch(void* const* d_in, const int* in_sizes, int n_in,
                              void* d_out, int out_size, void* d_ws, size_t ws_size,
                              hipStream_t stream) {
  const float* xyz = (const float*)d_in[0];
  const float* pts = (const float*)d_in[1];
  const float* W1 = (const float*)d_in[2],  *b1 = (const float*)d_in[3];
  const float* g1 = (const float*)d_in[4],  *be1 = (const float*)d_in[5];
  const float* W2 = (const float*)d_in[6],  *b2 = (const float*)d_in[7];
  const float* g2 = (const float*)d_in[8],  *be2 = (const float*)d_in[9];
  const float* W3 = (const float*)d_in[10], *b3 = (const float*)d_in[11];
  const float* g3 = (const float*)d_in[12], *be3 = (const float*)d_in[13];
  float* out0 = (float*)d_out;                 // xyz_query_pc [16,3,1024]
  float* out1 = out0 + B_ * 3 * S_;            // new_points   [16,128,1024]

  char* ws = (char*)d_ws;
  float* new_xyz  = (float*)(ws);              // 49152 floats
  float* bn1      = (float*)(ws + 196608);     // 128
  float* bn2      = bn1 + 128;                 // 128
  float* bn3      = bn2 + 128;                 // 256
  int*   gidx     = (int*)(ws + 198656);       // 524288 ints
  float* partials = (float*)(ws + 2295808);    // 256*PNB floats (1 MB)
  unsigned short* y1 = (unsigned short*)(ws + 4392960);           // 64 MB bf16
  unsigned short* y2 = (unsigned short*)(ws + 4392960 + 67108864); // 64 MB bf16

  fps_kernel<<<B_, 512, 0, stream>>>(xyz, out0, new_xyz);
  ballq_kernel<<<4096, 256, 0, stream>>>(xyz, new_xyz, gidx);
  layer1_kernel<<<PNB, 256, 0, stream>>>(xyz, pts, new_xyz, gidx, W1, b1, y1, partials);
  finalize_kernel<<<64, 256, 0, stream>>>(partials, 64, g1, be1, bn1);
  mfma_layer_kernel<4, true><<<PNB, 256, 0, stream>>>(y1, W2, b2, bn1, y2, partials);
  finalize_kernel<<<64, 256, 0, stream>>>(partials, 64, g2, be2, bn2);
  mfma_layer_kernel<8, false><<<PNB, 256, 0, stream>>>(y2, W3, b3, bn2, nullptr, partials);
  finalize_kernel<<<128, 256, 0, stream>>>(partials, 128, g3, be3, bn3);
  l3max_kernel<<<4096, 256, 0, stream>>>(y2, W3, b3, bn2, bn3, out1);
}

// Round 8
// 931.978 us; speedup vs baseline: 1.2770x; 1.1525x over previous
//
#include <hip/hip_runtime.h>

#pragma clang fp contract(off)

#define NPT 4096
#define B_ 16
#define S_ 1024
#define K_ 32
#define ROWS (B_*S_*K_)   // 524288
#define PNB 1024          // partial-stats blocks (layer kernels' grid)

typedef float v2f __attribute__((ext_vector_type(2)));
typedef unsigned int u32;
typedef unsigned long long u64;
typedef __attribute__((ext_vector_type(8))) short s16x8;
typedef __attribute__((ext_vector_type(4))) float f32x4;
typedef __attribute__((ext_vector_type(8))) unsigned short us8v;

// float readlane broadcast (SALU v_readlane -> scalar operand)
__device__ __forceinline__ float rlf(float v, int l) {
  return __uint_as_float(__builtin_amdgcn_readlane(__float_as_uint(v), l));
}

__device__ __forceinline__ short rne_bf16(float x) {
  u32 b = __float_as_uint(x);
  b += 0x7FFFu + ((b >> 16) & 1u);
  return (short)(b >> 16);
}
__device__ __forceinline__ float bf16_to_f(unsigned short h) {
  return __uint_as_float(((u32)h) << 16);
}

__device__ __forceinline__ f32x4 mfma16(s16x8 a, s16x8 b, f32x4 c) {
  return __builtin_amdgcn_mfma_f32_16x16x32_bf16(a, b, c, 0, 0, 0);
}

template <int CTRL>
__device__ __forceinline__ u64 dpp_u64(u64 x) {
  int lo = (int)(u32)x, hi = (int)(u32)(x >> 32);
  lo = __builtin_amdgcn_update_dpp(lo, lo, CTRL, 0xF, 0xF, false);
  hi = __builtin_amdgcn_update_dpp(hi, hi, CTRL, 0xF, 0xF, false);
  return ((u64)(u32)hi << 32) | (u32)lo;
}
// full-wave f64 max -> lane 63. Keys are positive doubles => f64 order == u64 order.
__device__ __forceinline__ double wave_max_f64(double k) {
  k = fmax(k, __longlong_as_double((long long)dpp_u64<0x111>((u64)__double_as_longlong(k))));
  k = fmax(k, __longlong_as_double((long long)dpp_u64<0x112>((u64)__double_as_longlong(k))));
  k = fmax(k, __longlong_as_double((long long)dpp_u64<0x114>((u64)__double_as_longlong(k))));
  k = fmax(k, __longlong_as_double((long long)dpp_u64<0x118>((u64)__double_as_longlong(k))));
  k = fmax(k, __longlong_as_double((long long)dpp_u64<0x142>((u64)__double_as_longlong(k))));
  k = fmax(k, __longlong_as_double((long long)dpp_u64<0x143>((u64)__double_as_longlong(k))));
  return k;
}

__device__ __forceinline__ double mkkey(float d, u32 lo) {
  return __longlong_as_double((long long)(((u64)__float_as_uint(d) << 32) | lo));
}

// ---------------- FPS: one block per batch, 512 threads, 8 pts/thread ----------------
// Proven-best structure (R5, 588 us): f64 packed keys, DPP wave max, lane63 LDS atomicMax.
__global__ __launch_bounds__(512) void fps_kernel(const float* __restrict__ xyz,
    float* __restrict__ out0, float* __restrict__ new_xyz) {
  const int b = blockIdx.x, t = threadIdx.x;
  const int lane = t & 63;
  const float* xb = xyz + (size_t)b * 3 * NPT;
  __shared__ float4 spt[NPT];       // 64 KB: (x,y,z,-)
  __shared__ u64 skey[3];           // 3-slot rotating argmax cell
  __shared__ int sfar[S_];          // selected index per iteration
  // coalesced stage into LDS
#pragma unroll
  for (int j = 0; j < 8; j++) {
    int m = t + j * 512;
    spt[m] = make_float4(xb[m], xb[NPT + m], xb[2 * NPT + m], 0.f);
  }
  if (t < 3) skey[t] = 0ull;
  // lane-local consecutive points n = t*8+i, loaded from global (coalesced float4)
  const float4* xb4 = (const float4*)xb;
  float4 X0 = xb4[t * 2], X1 = xb4[t * 2 + 1];
  float4 Y0 = xb4[NPT / 4 + t * 2], Y1 = xb4[NPT / 4 + t * 2 + 1];
  float4 Z0 = xb4[2 * NPT / 4 + t * 2], Z1 = xb4[2 * NPT / 4 + t * 2 + 1];
  v2f px[4], py[4], pz[4], ds[4];
  px[0] = (v2f){X0.x, X0.y}; px[1] = (v2f){X0.z, X0.w}; px[2] = (v2f){X1.x, X1.y}; px[3] = (v2f){X1.z, X1.w};
  py[0] = (v2f){Y0.x, Y0.y}; py[1] = (v2f){Y0.z, Y0.w}; py[2] = (v2f){Y1.x, Y1.y}; py[3] = (v2f){Y1.z, Y1.w};
  pz[0] = (v2f){Z0.x, Z0.y}; pz[1] = (v2f){Z0.z, Z0.w}; pz[2] = (v2f){Z1.x, Z1.y}; pz[3] = (v2f){Z1.z, Z1.w};
  const int base = t * 8;
  u32 lo[8];
#pragma unroll
  for (int i = 0; i < 8; i++) lo[i] = ~(u32)(base + i);
#pragma unroll
  for (int j = 0; j < 4; j++) ds[j] = (v2f){1e10f, 1e10f};
  __syncthreads();
  int far = 0, slot = 0;
  for (int it = 0; it < S_; ++it) {
    if (t == 0) sfar[it] = far;
    float4 c = spt[far];
    v2f cx = (v2f){c.x, c.x}, cy = (v2f){c.y, c.y}, cz = (v2f){c.z, c.z};
#pragma unroll
    for (int j = 0; j < 4; j++) {
      // exact ref op order per element: ((dx*dx + dy*dy) + dz*dz), contraction OFF
      v2f dx = px[j] - cx, dy = py[j] - cy, dz = pz[j] - cz;
      v2f s = dx * dx + dy * dy;
      v2f d = s + dz * dz;
      v2f nd;
      nd.x = fminf(ds[j].x, d.x);
      nd.y = fminf(ds[j].y, d.y);
      ds[j] = nd;
    }
    // f64 sortable keys: max dist, tie -> min index (via ~idx in low word)
    double k = fmax(fmax(fmax(mkkey(ds[0].x, lo[0]), mkkey(ds[0].y, lo[1])),
                         fmax(mkkey(ds[1].x, lo[2]), mkkey(ds[1].y, lo[3]))),
                    fmax(fmax(mkkey(ds[2].x, lo[4]), mkkey(ds[2].y, lo[5])),
                         fmax(mkkey(ds[3].x, lo[6]), mkkey(ds[3].y, lo[7]))));
    k = wave_max_f64(k);
    if (lane == 63) atomicMax(&skey[slot], (u64)__double_as_longlong(k));
    __syncthreads();
    u64 kk = skey[slot];
    if (t == 0) skey[slot == 0 ? 2 : slot - 1] = 0ull;  // reset slot (it+2)%3: safe post-barrier
    far = (int)(~(u32)kk);
    slot = (slot == 2) ? 0 : slot + 1;
  }
  __syncthreads();
  // coalesced writeback of centroids
#pragma unroll
  for (int j = 0; j < 2; j++) {
    int it = t + j * 512;
    float4 p = spt[sfar[it]];
    out0[(b * 3 + 0) * S_ + it] = p.x;
    out0[(b * 3 + 1) * S_ + it] = p.y;
    out0[(b * 3 + 2) * S_ + it] = p.z;
    float* nz = new_xyz + ((size_t)b * S_ + it) * 3;
    nz[0] = p.x; nz[1] = p.y; nz[2] = p.z;
  }
}

// ---------------- Ball query: one wave per query ----------------
__global__ __launch_bounds__(256) void ballq_kernel(const float* __restrict__ xyz,
    const float* __restrict__ new_xyz, int* __restrict__ gidx) {
  const int wid = (blockIdx.x * 256 + threadIdx.x) >> 6;   // 16384 queries
  const int lane = threadIdx.x & 63;
  const int b = wid >> 10;
  const float* xb = xyz + (size_t)b * 3 * NPT;
  const float qx = new_xyz[(size_t)wid * 3 + 0];
  const float qy = new_xyz[(size_t)wid * 3 + 1];
  const float qz = new_xyz[(size_t)wid * 3 + 2];
  const float R2 = (float)(0.4 * 0.4);
  int* g = gidx + (size_t)wid * K_;
  int cnt = 0, firstIdx = 0x7fffffff;
  for (int c0 = 0; c0 < NPT && cnt < K_; c0 += 64) {
    int n = c0 + lane;
    float dx = __fadd_rn(qx, -xb[n]);
    float dy = __fadd_rn(qy, -xb[NPT + n]);
    float dz = __fadd_rn(qz, -xb[2 * NPT + n]);
    float sq = __fadd_rn(__fadd_rn(__fmul_rn(dx, dx), __fmul_rn(dy, dy)), __fmul_rn(dz, dz));
    bool inr = !(sq > R2);
    unsigned long long m = __ballot(inr);
    if (inr) {
      int pos = cnt + (int)__popcll(m & ((1ull << lane) - 1ull));
      if (pos < K_) g[pos] = n;
    }
    if (firstIdx == 0x7fffffff && m) firstIdx = c0 + (int)__builtin_ctzll(m);
    cnt += (int)__popcll(m);
  }
  if (lane >= cnt && lane < K_) g[lane] = firstIdx;  // pad with first (always exists: self)
}

// ---------------- Layer 1: gather+concat fused, 6->64, bf16 out + partial stats ----------------
__global__ __launch_bounds__(256) void layer1_kernel(
    const float* __restrict__ xyz, const float* __restrict__ pts,
    const float* __restrict__ new_xyz, const int* __restrict__ gidx,
    const float* __restrict__ W1, const float* __restrict__ b1,
    unsigned short* __restrict__ y1, float* __restrict__ partials) {
  __shared__ float sp[4 * 2 * 64];
  const int lane = threadIdx.x & 63, wv = threadIdx.x >> 6;
  const int nw = gridDim.x * 4;
  float w[6];
#pragma unroll
  for (int c = 0; c < 6; c++) w[c] = W1[lane * 6 + c];
  const float bias = b1[lane];
  float s0 = 0.f, s1 = 0.f;
  for (int r = blockIdx.x * 4 + wv; r < ROWS; r += nw) {
    int gi = gidx[r];
    int bs = r >> 5, b = bs >> 10;
    float v = 0.f;
    if (lane < 3)      v = xyz[((size_t)b * 3 + lane) * NPT + gi] - new_xyz[(size_t)bs * 3 + lane];
    else if (lane < 6) v = pts[((size_t)b * 3 + (lane - 3)) * NPT + gi];
    float acc = bias;
#pragma unroll
    for (int c = 0; c < 6; c++) acc = fmaf(rlf(v, c), w[c], acc);
    y1[(size_t)r * 64 + lane] = (unsigned short)rne_bf16(acc);
    s0 += acc; s1 = fmaf(acc, acc, s1);
  }
  sp[(wv * 2 + 0) * 64 + lane] = s0;
  sp[(wv * 2 + 1) * 64 + lane] = s1;
  __syncthreads();
  if (threadIdx.x < 128) {
    float p = sp[threadIdx.x] + sp[threadIdx.x + 128] + sp[threadIdx.x + 256] + sp[threadIdx.x + 384];
    partials[(size_t)threadIdx.x * PNB + blockIdx.x] = p;   // transposed: [stat_row][block]
  }
}

// ---------------- MFMA layer: bn(prev)+relu -> bf16 -> GEMM(64->NT*16) + stats ----------------
template <int NT, bool WRITE_OUT>
__global__ __launch_bounds__(256) void mfma_layer_kernel(
    const unsigned short* __restrict__ yin,   // [M][64] bf16 pre-BN
    const float* __restrict__ W,              // [NT*16][64] f32
    const float* __restrict__ bias,           // [NT*16]
    const float* __restrict__ bnin,           // scale[64], shift[64]
    unsigned short* __restrict__ yout,        // [M][NT*16] bf16 pre-BN (or unused)
    float* __restrict__ partials) {
  constexpr int COUT = NT * 16;
  const int lane = threadIdx.x & 63, wv = threadIdx.x >> 6;
  const int quad = lane >> 4, l16 = lane & 15;
  // loop-invariants: B-frags (W is [n][k] = exactly B-operand layout), bias, input BN
  s16x8 bfrag[NT][2];
  float biasr[NT];
#pragma unroll
  for (int t = 0; t < NT; t++) {
    int n = l16 + 16 * t;
    biasr[t] = bias[n];
#pragma unroll
    for (int kc = 0; kc < 2; kc++)
#pragma unroll
      for (int j = 0; j < 8; j++)
        bfrag[t][kc][j] = rne_bf16(W[(size_t)n * 64 + kc * 32 + quad * 8 + j]);
  }
  float isc[2][8], ish[2][8];
#pragma unroll
  for (int kc = 0; kc < 2; kc++)
#pragma unroll
    for (int j = 0; j < 8; j++) {
      int k = kc * 32 + quad * 8 + j;
      isc[kc][j] = bnin[k]; ish[kc][j] = bnin[64 + k];
    }
  float s0[NT], s1[NT];
#pragma unroll
  for (int t = 0; t < NT; t++) { s0[t] = 0.f; s1[t] = 0.f; }
  const int nwaves = gridDim.x * 4;
  for (int mt = blockIdx.x * 4 + wv; mt < ROWS / 16; mt += nwaves) {
    int row = mt * 16 + l16;
    const unsigned short* p = yin + (size_t)row * 64 + quad * 8;
    us8v r0 = *(const us8v*)p;
    us8v r1 = *(const us8v*)(p + 32);
    s16x8 a0, a1;
#pragma unroll
    for (int j = 0; j < 8; j++) {
      float z0 = fmaxf(fmaf(bf16_to_f(r0[j]), isc[0][j], ish[0][j]), 0.f);
      float z1 = fmaxf(fmaf(bf16_to_f(r1[j]), isc[1][j], ish[1][j]), 0.f);
      a0[j] = rne_bf16(z0); a1[j] = rne_bf16(z1);
    }
    f32x4 acc[NT];
#pragma unroll
    for (int t = 0; t < NT; t++) {
      acc[t] = (f32x4){biasr[t], biasr[t], biasr[t], biasr[t]};
      acc[t] = mfma16(a0, bfrag[t][0], acc[t]);
      acc[t] = mfma16(a1, bfrag[t][1], acc[t]);
    }
#pragma unroll
    for (int t = 0; t < NT; t++) {
#pragma unroll
      for (int r = 0; r < 4; r++) {
        float v = acc[t][r];                       // D[row=quad*4+r][col=l16+16t]
        s0[t] += v; s1[t] = fmaf(v, v, s1[t]);
        if (WRITE_OUT) {
          int m = mt * 16 + quad * 4 + r;
          yout[(size_t)m * COUT + l16 + 16 * t] = (unsigned short)rne_bf16(v);
        }
      }
    }
  }
  // reduce stats: lanes {n, n+16, n+32, n+48} hold the same channel
#pragma unroll
  for (int t = 0; t < NT; t++) {
    s0[t] += __shfl_xor(s0[t], 16); s0[t] += __shfl_xor(s0[t], 32);
    s1[t] += __shfl_xor(s1[t], 16); s1[t] += __shfl_xor(s1[t], 32);
  }
  __shared__ float sp[4 * 2 * COUT];
  if (quad == 0) {
#pragma unroll
    for (int t = 0; t < NT; t++) {
      sp[wv * 2 * COUT + l16 + 16 * t] = s0[t];
      sp[wv * 2 * COUT + COUT + l16 + 16 * t] = s1[t];
    }
  }
  __syncthreads();
  for (int tt = threadIdx.x; tt < 2 * COUT; tt += 256) {
    float p = sp[tt] + sp[2 * COUT + tt] + sp[4 * COUT + tt] + sp[6 * COUT + tt];
    partials[(size_t)tt * PNB + blockIdx.x] = p;
  }
}

// ---------------- fold partials -> bn scale/shift (one block per channel) ----------------
__global__ __launch_bounds__(256) void finalize_kernel(const float* __restrict__ partials,
    int cout, const float* __restrict__ g, const float* __restrict__ be,
    float* __restrict__ bn) {
  const int c = blockIdx.x;
  const int t = threadIdx.x;
  const int lane = t & 63, wv = t >> 6;
  float s0 = 0.f, s1 = 0.f;
  for (int bb = t; bb < PNB; bb += 256) {
    s0 += partials[(size_t)c * PNB + bb];
    s1 += partials[(size_t)(cout + c) * PNB + bb];
  }
#pragma unroll
  for (int off = 32; off; off >>= 1) {
    s0 += __shfl_xor(s0, off);
    s1 += __shfl_xor(s1, off);
  }
  __shared__ float r0[4], r1[4];
  if (lane == 0) { r0[wv] = s0; r1[wv] = s1; }
  __syncthreads();
  if (t == 0) {
    double d0 = (double)r0[0] + r0[1] + r0[2] + r0[3];
    double d1 = (double)r1[0] + r1[1] + r1[2] + r1[3];
    double N = (double)ROWS;
    double mean = d0 / N;
    double var = d1 / N - mean * mean;
    double scale = (double)g[c] / sqrt(var + 1e-5);
    bn[c] = (float)scale;
    bn[cout + c] = (float)((double)be[c] - mean * scale);
  }
}

// ---------------- Layer3 recompute (MFMA) + bn3 + relu + max over K + transposed store ----
// Grid-stride over 4 group-chunks per block: amortizes the 128-load W3/bn setup 4x per wave.
__global__ __launch_bounds__(256) void l3max_kernel(
    const unsigned short* __restrict__ y2, const float* __restrict__ W3,
    const float* __restrict__ b3, const float* __restrict__ bn2,
    const float* __restrict__ bn3, float* __restrict__ out1) {
  constexpr int NT = 8;
  const int lane = threadIdx.x & 63, wv = threadIdx.x >> 6;
  const int quad = lane >> 4, l16 = lane & 15;
  s16x8 bfrag[NT][2];
  float biasr[NT], s3[NT], h3[NT];
#pragma unroll
  for (int t = 0; t < NT; t++) {
    int n = l16 + 16 * t;
    biasr[t] = b3[n]; s3[t] = bn3[n]; h3[t] = bn3[128 + n];
#pragma unroll
    for (int kc = 0; kc < 2; kc++)
#pragma unroll
      for (int j = 0; j < 8; j++)
        bfrag[t][kc][j] = rne_bf16(W3[(size_t)n * 64 + kc * 32 + quad * 8 + j]);
  }
  float isc[2][8], ish[2][8];
#pragma unroll
  for (int kc = 0; kc < 2; kc++)
#pragma unroll
    for (int j = 0; j < 8; j++) {
      int k = kc * 32 + quad * 8 + j;
      isc[kc][j] = bn2[k]; ish[kc][j] = bn2[64 + k];
    }
  __shared__ float tile[128 * 4];   // [ch][s_local]
  for (int g0 = blockIdx.x; g0 < 4096; g0 += 1024) {
    const int gq = g0 * 4 + wv;     // group = (b,s) pair; 4 consecutive s per block
    float mx[NT];
#pragma unroll
    for (int t = 0; t < NT; t++) mx[t] = -1e30f;
#pragma unroll
    for (int mt2 = 0; mt2 < 2; mt2++) {          // 32 rows = 2 M-tiles
      int row = gq * 32 + mt2 * 16 + l16;
      const unsigned short* p = y2 + (size_t)row * 64 + quad * 8;
      us8v r0 = *(const us8v*)p;
      us8v r1 = *(const us8v*)(p + 32);
      s16x8 a0, a1;
#pragma unroll
      for (int j = 0; j < 8; j++) {
        float z0 = fmaxf(fmaf(bf16_to_f(r0[j]), isc[0][j], ish[0][j]), 0.f);
        float z1 = fmaxf(fmaf(bf16_to_f(r1[j]), isc[1][j], ish[1][j]), 0.f);
        a0[j] = rne_bf16(z0); a1[j] = rne_bf16(z1);
      }
#pragma unroll
      for (int t = 0; t < NT; t++) {
        f32x4 acc = (f32x4){biasr[t], biasr[t], biasr[t], biasr[t]};
        acc = mfma16(a0, bfrag[t][0], acc);
        acc = mfma16(a1, bfrag[t][1], acc);
#pragma unroll
        for (int r = 0; r < 4; r++) {
          float z = fmaxf(fmaf(acc[r], s3[t], h3[t]), 0.f);
          mx[t] = fmaxf(mx[t], z);
        }
      }
    }
#pragma unroll
    for (int t = 0; t < NT; t++) {
      mx[t] = fmaxf(mx[t], __shfl_xor(mx[t], 16));
      mx[t] = fmaxf(mx[t], __shfl_xor(mx[t], 32));
    }
    if (quad == 0) {
#pragma unroll
      for (int t = 0; t < NT; t++) tile[(l16 + 16 * t) * 4 + wv] = mx[t];
    }
    __syncthreads();
    if (threadIdx.x < 128) {
      int b = g0 >> 8;              // 256 group-chunks per batch
      int s0i = (g0 & 255) * 4;
      float4 vv = *(float4*)&tile[threadIdx.x * 4];
      *(float4*)&out1[((size_t)b * 128 + threadIdx.x) * 1024 + s0i] = vv;
    }
    __syncthreads();                // tile reused next chunk
  }
}

extern "C" void kernel_launch(void* const* d_in, const int* in_sizes, int n_in,
                              void* d_out, int out_size, void* d_ws, size_t ws_size,
                              hipStream_t stream) {
  const float* xyz = (const float*)d_in[0];
  const float* pts = (const float*)d_in[1];
  const float* W1 = (const float*)d_in[2],  *b1 = (const float*)d_in[3];
  const float* g1 = (const float*)d_in[4],  *be1 = (const float*)d_in[5];
  const float* W2 = (const float*)d_in[6],  *b2 = (const float*)d_in[7];
  const float* g2 = (const float*)d_in[8],  *be2 = (const float*)d_in[9];
  const float* W3 = (const float*)d_in[10], *b3 = (const float*)d_in[11];
  const float* g3 = (const float*)d_in[12], *be3 = (const float*)d_in[13];
  float* out0 = (float*)d_out;                 // xyz_query_pc [16,3,1024]
  float* out1 = out0 + B_ * 3 * S_;            // new_points   [16,128,1024]

  char* ws = (char*)d_ws;
  float* new_xyz  = (float*)(ws);              // 49152 floats
  float* bn1      = (float*)(ws + 196608);     // 128
  float* bn2      = bn1 + 128;                 // 128
  float* bn3      = bn2 + 128;                 // 256
  int*   gidx     = (int*)(ws + 198656);       // 524288 ints
  float* partials = (float*)(ws + 2295808);    // 256*PNB floats (1 MB)
  unsigned short* y1 = (unsigned short*)(ws + 4392960);           // 64 MB bf16
  unsigned short* y2 = (unsigned short*)(ws + 4392960 + 67108864); // 64 MB bf16

  fps_kernel<<<B_, 512, 0, stream>>>(xyz, out0, new_xyz);
  ballq_kernel<<<4096, 256, 0, stream>>>(xyz, new_xyz, gidx);
  layer1_kernel<<<PNB, 256, 0, stream>>>(xyz, pts, new_xyz, gidx, W1, b1, y1, partials);
  finalize_kernel<<<64, 256, 0, stream>>>(partials, 64, g1, be1, bn1);
  mfma_layer_kernel<4, true><<<PNB, 256, 0, stream>>>(y1, W2, b2, bn1, y2, partials);
  finalize_kernel<<<64, 256, 0, stream>>>(partials, 64, g2, be2, bn2);
  mfma_layer_kernel<8, false><<<PNB, 256, 0, stream>>>(y2, W3, b3, bn2, nullptr, partials);
  finalize_kernel<<<128, 256, 0, stream>>>(partials, 128, g3, be3, bn3);
  l3max_kernel<<<1024, 256, 0, stream>>>(y2, W3, b3, bn2, bn3, out1);
}

// Round 9
// 926.088 us; speedup vs baseline: 1.2851x; 1.0064x over previous
//
#include <hip/hip_runtime.h>

#pragma clang fp contract(off)

#define NPT 4096
#define B_ 16
#define S_ 1024
#define K_ 32
#define ROWS (B_*S_*K_)   // 524288
#define PNB 1024          // partial-stats blocks (layer kernels' grid)

typedef float v2f __attribute__((ext_vector_type(2)));
typedef unsigned int u32;
typedef unsigned long long u64;
typedef __attribute__((ext_vector_type(8))) short s16x8;
typedef __attribute__((ext_vector_type(4))) float f32x4;
typedef __attribute__((ext_vector_type(8))) unsigned short us8v;

// float readlane broadcast (SALU v_readlane -> scalar operand)
__device__ __forceinline__ float rlf(float v, int l) {
  return __uint_as_float(__builtin_amdgcn_readlane(__float_as_uint(v), l));
}

__device__ __forceinline__ short rne_bf16(float x) {
  u32 b = __float_as_uint(x);
  b += 0x7FFFu + ((b >> 16) & 1u);
  return (short)(b >> 16);
}
__device__ __forceinline__ float bf16_to_f(unsigned short h) {
  return __uint_as_float(((u32)h) << 16);
}

__device__ __forceinline__ f32x4 mfma16(s16x8 a, s16x8 b, f32x4 c) {
  return __builtin_amdgcn_mfma_f32_16x16x32_bf16(a, b, c, 0, 0, 0);
}

template <int CTRL>
__device__ __forceinline__ u64 dpp_u64(u64 x) {
  int lo = (int)(u32)x, hi = (int)(u32)(x >> 32);
  lo = __builtin_amdgcn_update_dpp(lo, lo, CTRL, 0xF, 0xF, false);
  hi = __builtin_amdgcn_update_dpp(hi, hi, CTRL, 0xF, 0xF, false);
  return ((u64)(u32)hi << 32) | (u32)lo;
}
// full-wave f64 max -> lane 63. Keys are positive doubles => f64 order == u64 order.
__device__ __forceinline__ double wave_max_f64(double k) {
  k = fmax(k, __longlong_as_double((long long)dpp_u64<0x111>((u64)__double_as_longlong(k))));
  k = fmax(k, __longlong_as_double((long long)dpp_u64<0x112>((u64)__double_as_longlong(k))));
  k = fmax(k, __longlong_as_double((long long)dpp_u64<0x114>((u64)__double_as_longlong(k))));
  k = fmax(k, __longlong_as_double((long long)dpp_u64<0x118>((u64)__double_as_longlong(k))));
  k = fmax(k, __longlong_as_double((long long)dpp_u64<0x142>((u64)__double_as_longlong(k))));
  k = fmax(k, __longlong_as_double((long long)dpp_u64<0x143>((u64)__double_as_longlong(k))));
  return k;
}

__device__ __forceinline__ double mkkey(float d, u32 lo) {
  return __longlong_as_double((long long)(((u64)__float_as_uint(d) << 32) | lo));
}

// ---------------- FPS: one block per batch, 512 threads, 8 pts/thread ----------------
// Proven-best structure (R5/R8, 588 us): f64 packed keys, DPP wave max, lane63 LDS atomicMax.
// DO NOT retune: 256-thread (R6) and value-then-resolve (R7) variants both regressed.
__global__ __launch_bounds__(512) void fps_kernel(const float* __restrict__ xyz,
    float* __restrict__ out0, float* __restrict__ new_xyz) {
  const int b = blockIdx.x, t = threadIdx.x;
  const int lane = t & 63;
  const float* xb = xyz + (size_t)b * 3 * NPT;
  __shared__ float4 spt[NPT];       // 64 KB: (x,y,z,-)
  __shared__ u64 skey[3];           // 3-slot rotating argmax cell
  __shared__ int sfar[S_];          // selected index per iteration
  // coalesced stage into LDS
#pragma unroll
  for (int j = 0; j < 8; j++) {
    int m = t + j * 512;
    spt[m] = make_float4(xb[m], xb[NPT + m], xb[2 * NPT + m], 0.f);
  }
  if (t < 3) skey[t] = 0ull;
  // lane-local consecutive points n = t*8+i, loaded from global (coalesced float4)
  const float4* xb4 = (const float4*)xb;
  float4 X0 = xb4[t * 2], X1 = xb4[t * 2 + 1];
  float4 Y0 = xb4[NPT / 4 + t * 2], Y1 = xb4[NPT / 4 + t * 2 + 1];
  float4 Z0 = xb4[2 * NPT / 4 + t * 2], Z1 = xb4[2 * NPT / 4 + t * 2 + 1];
  v2f px[4], py[4], pz[4], ds[4];
  px[0] = (v2f){X0.x, X0.y}; px[1] = (v2f){X0.z, X0.w}; px[2] = (v2f){X1.x, X1.y}; px[3] = (v2f){X1.z, X1.w};
  py[0] = (v2f){Y0.x, Y0.y}; py[1] = (v2f){Y0.z, Y0.w}; py[2] = (v2f){Y1.x, Y1.y}; py[3] = (v2f){Y1.z, Y1.w};
  pz[0] = (v2f){Z0.x, Z0.y}; pz[1] = (v2f){Z0.z, Z0.w}; pz[2] = (v2f){Z1.x, Z1.y}; pz[3] = (v2f){Z1.z, Z1.w};
  const int base = t * 8;
  u32 lo[8];
#pragma unroll
  for (int i = 0; i < 8; i++) lo[i] = ~(u32)(base + i);
#pragma unroll
  for (int j = 0; j < 4; j++) ds[j] = (v2f){1e10f, 1e10f};
  __syncthreads();
  int far = 0, slot = 0;
  for (int it = 0; it < S_; ++it) {
    if (t == 0) sfar[it] = far;
    float4 c = spt[far];
    v2f cx = (v2f){c.x, c.x}, cy = (v2f){c.y, c.y}, cz = (v2f){c.z, c.z};
#pragma unroll
    for (int j = 0; j < 4; j++) {
      // exact ref op order per element: ((dx*dx + dy*dy) + dz*dz), contraction OFF
      v2f dx = px[j] - cx, dy = py[j] - cy, dz = pz[j] - cz;
      v2f s = dx * dx + dy * dy;
      v2f d = s + dz * dz;
      v2f nd;
      nd.x = fminf(ds[j].x, d.x);
      nd.y = fminf(ds[j].y, d.y);
      ds[j] = nd;
    }
    // f64 sortable keys: max dist, tie -> min index (via ~idx in low word)
    double k = fmax(fmax(fmax(mkkey(ds[0].x, lo[0]), mkkey(ds[0].y, lo[1])),
                         fmax(mkkey(ds[1].x, lo[2]), mkkey(ds[1].y, lo[3]))),
                    fmax(fmax(mkkey(ds[2].x, lo[4]), mkkey(ds[2].y, lo[5])),
                         fmax(mkkey(ds[3].x, lo[6]), mkkey(ds[3].y, lo[7]))));
    k = wave_max_f64(k);
    if (lane == 63) atomicMax(&skey[slot], (u64)__double_as_longlong(k));
    __syncthreads();
    u64 kk = skey[slot];
    if (t == 0) skey[slot == 0 ? 2 : slot - 1] = 0ull;  // reset slot (it+2)%3: safe post-barrier
    far = (int)(~(u32)kk);
    slot = (slot == 2) ? 0 : slot + 1;
  }
  __syncthreads();
  // coalesced writeback of centroids
#pragma unroll
  for (int j = 0; j < 2; j++) {
    int it = t + j * 512;
    float4 p = spt[sfar[it]];
    out0[(b * 3 + 0) * S_ + it] = p.x;
    out0[(b * 3 + 1) * S_ + it] = p.y;
    out0[(b * 3 + 2) * S_ + it] = p.z;
    float* nz = new_xyz + ((size_t)b * S_ + it) * 3;
    nz[0] = p.x; nz[1] = p.y; nz[2] = p.z;
  }
}

// ---------------- Ball query: one wave per query ----------------
__global__ __launch_bounds__(256) void ballq_kernel(const float* __restrict__ xyz,
    const float* __restrict__ new_xyz, int* __restrict__ gidx) {
  const int wid = (blockIdx.x * 256 + threadIdx.x) >> 6;   // 16384 queries
  const int lane = threadIdx.x & 63;
  const int b = wid >> 10;
  const float* xb = xyz + (size_t)b * 3 * NPT;
  const float qx = new_xyz[(size_t)wid * 3 + 0];
  const float qy = new_xyz[(size_t)wid * 3 + 1];
  const float qz = new_xyz[(size_t)wid * 3 + 2];
  const float R2 = (float)(0.4 * 0.4);
  int* g = gidx + (size_t)wid * K_;
  int cnt = 0, firstIdx = 0x7fffffff;
  for (int c0 = 0; c0 < NPT && cnt < K_; c0 += 64) {
    int n = c0 + lane;
    float dx = __fadd_rn(qx, -xb[n]);
    float dy = __fadd_rn(qy, -xb[NPT + n]);
    float dz = __fadd_rn(qz, -xb[2 * NPT + n]);
    float sq = __fadd_rn(__fadd_rn(__fmul_rn(dx, dx), __fmul_rn(dy, dy)), __fmul_rn(dz, dz));
    bool inr = !(sq > R2);
    unsigned long long m = __ballot(inr);
    if (inr) {
      int pos = cnt + (int)__popcll(m & ((1ull << lane) - 1ull));
      if (pos < K_) g[pos] = n;
    }
    if (firstIdx == 0x7fffffff && m) firstIdx = c0 + (int)__builtin_ctzll(m);
    cnt += (int)__popcll(m);
  }
  if (lane >= cnt && lane < K_) g[lane] = firstIdx;  // pad with first (always exists: self)
}

// ---------------- Layer 1: gather+concat fused, 6->64, bf16 out + partial stats ----------------
__global__ __launch_bounds__(256) void layer1_kernel(
    const float* __restrict__ xyz, const float* __restrict__ pts,
    const float* __restrict__ new_xyz, const int* __restrict__ gidx,
    const float* __restrict__ W1, const float* __restrict__ b1,
    unsigned short* __restrict__ y1, float* __restrict__ partials) {
  __shared__ float sp[4 * 2 * 64];
  const int lane = threadIdx.x & 63, wv = threadIdx.x >> 6;
  const int nw = gridDim.x * 4;
  float w[6];
#pragma unroll
  for (int c = 0; c < 6; c++) w[c] = W1[lane * 6 + c];
  const float bias = b1[lane];
  float s0 = 0.f, s1 = 0.f;
  for (int r = blockIdx.x * 4 + wv; r < ROWS; r += nw) {
    int gi = gidx[r];
    int bs = r >> 5, b = bs >> 10;
    float v = 0.f;
    if (lane < 3)      v = xyz[((size_t)b * 3 + lane) * NPT + gi] - new_xyz[(size_t)bs * 3 + lane];
    else if (lane < 6) v = pts[((size_t)b * 3 + (lane - 3)) * NPT + gi];
    float acc = bias;
#pragma unroll
    for (int c = 0; c < 6; c++) acc = fmaf(rlf(v, c), w[c], acc);
    y1[(size_t)r * 64 + lane] = (unsigned short)rne_bf16(acc);
    s0 += acc; s1 = fmaf(acc, acc, s1);
  }
  sp[(wv * 2 + 0) * 64 + lane] = s0;
  sp[(wv * 2 + 1) * 64 + lane] = s1;
  __syncthreads();
  if (threadIdx.x < 128) {
    float p = sp[threadIdx.x] + sp[threadIdx.x + 128] + sp[threadIdx.x + 256] + sp[threadIdx.x + 384];
    partials[(size_t)threadIdx.x * PNB + blockIdx.x] = p;   // transposed: [stat_row][block]
  }
}

// ---------------- MFMA layer 2: bn1+relu -> bf16 -> GEMM(64->64) + stats, writes y2 ----------------
template <int NT, bool WRITE_OUT>
__global__ __launch_bounds__(256) void mfma_layer_kernel(
    const unsigned short* __restrict__ yin,   // [M][64] bf16 pre-BN
    const float* __restrict__ W,              // [NT*16][64] f32
    const float* __restrict__ bias,           // [NT*16]
    const float* __restrict__ bnin,           // scale[64], shift[64]
    unsigned short* __restrict__ yout,        // [M][NT*16] bf16 pre-BN (or unused)
    float* __restrict__ partials) {
  constexpr int COUT = NT * 16;
  const int lane = threadIdx.x & 63, wv = threadIdx.x >> 6;
  const int quad = lane >> 4, l16 = lane & 15;
  // loop-invariants: B-frags (W is [n][k] = exactly B-operand layout), bias, input BN
  s16x8 bfrag[NT][2];
  float biasr[NT];
#pragma unroll
  for (int t = 0; t < NT; t++) {
    int n = l16 + 16 * t;
    biasr[t] = bias[n];
#pragma unroll
    for (int kc = 0; kc < 2; kc++)
#pragma unroll
      for (int j = 0; j < 8; j++)
        bfrag[t][kc][j] = rne_bf16(W[(size_t)n * 64 + kc * 32 + quad * 8 + j]);
  }
  float isc[2][8], ish[2][8];
#pragma unroll
  for (int kc = 0; kc < 2; kc++)
#pragma unroll
    for (int j = 0; j < 8; j++) {
      int k = kc * 32 + quad * 8 + j;
      isc[kc][j] = bnin[k]; ish[kc][j] = bnin[64 + k];
    }
  float s0[NT], s1[NT];
#pragma unroll
  for (int t = 0; t < NT; t++) { s0[t] = 0.f; s1[t] = 0.f; }
  const int nwaves = gridDim.x * 4;
  for (int mt = blockIdx.x * 4 + wv; mt < ROWS / 16; mt += nwaves) {
    int row = mt * 16 + l16;
    const unsigned short* p = yin + (size_t)row * 64 + quad * 8;
    us8v r0 = *(const us8v*)p;
    us8v r1 = *(const us8v*)(p + 32);
    s16x8 a0, a1;
#pragma unroll
    for (int j = 0; j < 8; j++) {
      float z0 = fmaxf(fmaf(bf16_to_f(r0[j]), isc[0][j], ish[0][j]), 0.f);
      float z1 = fmaxf(fmaf(bf16_to_f(r1[j]), isc[1][j], ish[1][j]), 0.f);
      a0[j] = rne_bf16(z0); a1[j] = rne_bf16(z1);
    }
    f32x4 acc[NT];
#pragma unroll
    for (int t = 0; t < NT; t++) {
      acc[t] = (f32x4){biasr[t], biasr[t], biasr[t], biasr[t]};
      acc[t] = mfma16(a0, bfrag[t][0], acc[t]);
      acc[t] = mfma16(a1, bfrag[t][1], acc[t]);
    }
#pragma unroll
    for (int t = 0; t < NT; t++) {
#pragma unroll
      for (int r = 0; r < 4; r++) {
        float v = acc[t][r];                       // D[row=quad*4+r][col=l16+16t]
        s0[t] += v; s1[t] = fmaf(v, v, s1[t]);
        if (WRITE_OUT) {
          int m = mt * 16 + quad * 4 + r;
          yout[(size_t)m * COUT + l16 + 16 * t] = (unsigned short)rne_bf16(v);
        }
      }
    }
  }
  // reduce stats: lanes {n, n+16, n+32, n+48} hold the same channel
#pragma unroll
  for (int t = 0; t < NT; t++) {
    s0[t] += __shfl_xor(s0[t], 16); s0[t] += __shfl_xor(s0[t], 32);
    s1[t] += __shfl_xor(s1[t], 16); s1[t] += __shfl_xor(s1[t], 32);
  }
  __shared__ float sp[4 * 2 * COUT];
  if (quad == 0) {
#pragma unroll
    for (int t = 0; t < NT; t++) {
      sp[wv * 2 * COUT + l16 + 16 * t] = s0[t];
      sp[wv * 2 * COUT + COUT + l16 + 16 * t] = s1[t];
    }
  }
  __syncthreads();
  for (int tt = threadIdx.x; tt < 2 * COUT; tt += 256) {
    float p = sp[tt] + sp[2 * COUT + tt] + sp[4 * COUT + tt] + sp[6 * COUT + tt];
    partials[(size_t)tt * PNB + blockIdx.x] = p;
  }
}

// ---------------- fold partials -> bn scale/shift (one block per channel) ----------------
__global__ __launch_bounds__(256) void finalize_kernel(const float* __restrict__ partials,
    int cout, const float* __restrict__ g, const float* __restrict__ be,
    float* __restrict__ bn) {
  const int c = blockIdx.x;
  const int t = threadIdx.x;
  const int lane = t & 63, wv = t >> 6;
  float s0 = 0.f, s1 = 0.f;
  for (int bb = t; bb < PNB; bb += 256) {
    s0 += partials[(size_t)c * PNB + bb];
    s1 += partials[(size_t)(cout + c) * PNB + bb];
  }
#pragma unroll
  for (int off = 32; off; off >>= 1) {
    s0 += __shfl_xor(s0, off);
    s1 += __shfl_xor(s1, off);
  }
  __shared__ float r0[4], r1[4];
  if (lane == 0) { r0[wv] = s0; r1[wv] = s1; }
  __syncthreads();
  if (t == 0) {
    double d0 = (double)r0[0] + r0[1] + r0[2] + r0[3];
    double d1 = (double)r1[0] + r1[1] + r1[2] + r1[3];
    double N = (double)ROWS;
    double mean = d0 / N;
    double var = d1 / N - mean * mean;
    double scale = (double)g[c] / sqrt(var + 1e-5);
    bn[c] = (float)scale;
    bn[cout + c] = (float)((double)be[c] - mean * scale);
  }
}

// ---------------- Fused layer3: GEMM once -> stats partials + per-group min/max of raw y3 ----
// max_k relu(s*x+h) == relu(s*(s>0?max_k x:min_k x)+h)  (monotone affine + relu), so we only
// need the extremal raw x per (b,s,channel); bn3 applied in the tiny epilogue after finalize3.
__global__ __launch_bounds__(256) void l3fused_kernel(
    const unsigned short* __restrict__ y2, const float* __restrict__ W3,
    const float* __restrict__ b3, const float* __restrict__ bn2,
    float* __restrict__ mnbuf, float* __restrict__ mxbuf,   // [b][ch][s] f32
    float* __restrict__ partials) {
  constexpr int NT = 8;
  const int lane = threadIdx.x & 63, wv = threadIdx.x >> 6;
  const int quad = lane >> 4, l16 = lane & 15;
  s16x8 bfrag[NT][2];
  float biasr[NT];
#pragma unroll
  for (int t = 0; t < NT; t++) {
    int n = l16 + 16 * t;
    biasr[t] = b3[n];
#pragma unroll
    for (int kc = 0; kc < 2; kc++)
#pragma unroll
      for (int j = 0; j < 8; j++)
        bfrag[t][kc][j] = rne_bf16(W3[(size_t)n * 64 + kc * 32 + quad * 8 + j]);
  }
  float isc[2][8], ish[2][8];
#pragma unroll
  for (int kc = 0; kc < 2; kc++)
#pragma unroll
    for (int j = 0; j < 8; j++) {
      int k = kc * 32 + quad * 8 + j;
      isc[kc][j] = bn2[k]; ish[kc][j] = bn2[64 + k];
    }
  float s0[NT], s1[NT];
#pragma unroll
  for (int t = 0; t < NT; t++) { s0[t] = 0.f; s1[t] = 0.f; }
  __shared__ float tmx[128 * 4], tmn[128 * 4];   // [ch][s_local]
  for (int g0 = blockIdx.x; g0 < 4096; g0 += 1024) {
    const int gq = g0 * 4 + wv;                  // group = (b,s); 4 consecutive s per chunk
    float mx[NT], mn[NT];
#pragma unroll
    for (int t = 0; t < NT; t++) { mx[t] = -1e30f; mn[t] = 1e30f; }
#pragma unroll
    for (int mt2 = 0; mt2 < 2; mt2++) {          // 32 rows = 2 M-tiles
      int row = gq * 32 + mt2 * 16 + l16;
      const unsigned short* p = y2 + (size_t)row * 64 + quad * 8;
      us8v r0 = *(const us8v*)p;
      us8v r1 = *(const us8v*)(p + 32);
      s16x8 a0, a1;
#pragma unroll
      for (int j = 0; j < 8; j++) {
        float z0 = fmaxf(fmaf(bf16_to_f(r0[j]), isc[0][j], ish[0][j]), 0.f);
        float z1 = fmaxf(fmaf(bf16_to_f(r1[j]), isc[1][j], ish[1][j]), 0.f);
        a0[j] = rne_bf16(z0); a1[j] = rne_bf16(z1);
      }
#pragma unroll
      for (int t = 0; t < NT; t++) {
        f32x4 acc = (f32x4){biasr[t], biasr[t], biasr[t], biasr[t]};
        acc = mfma16(a0, bfrag[t][0], acc);
        acc = mfma16(a1, bfrag[t][1], acc);
#pragma unroll
        for (int r = 0; r < 4; r++) {
          float v = acc[r];
          s0[t] += v; s1[t] = fmaf(v, v, s1[t]);
          mx[t] = fmaxf(mx[t], v); mn[t] = fminf(mn[t], v);
        }
      }
    }
#pragma unroll
    for (int t = 0; t < NT; t++) {
      mx[t] = fmaxf(mx[t], __shfl_xor(mx[t], 16));
      mx[t] = fmaxf(mx[t], __shfl_xor(mx[t], 32));
      mn[t] = fminf(mn[t], __shfl_xor(mn[t], 16));
      mn[t] = fminf(mn[t], __shfl_xor(mn[t], 32));
    }
    if (quad == 0) {
#pragma unroll
      for (int t = 0; t < NT; t++) {
        tmx[(l16 + 16 * t) * 4 + wv] = mx[t];
        tmn[(l16 + 16 * t) * 4 + wv] = mn[t];
      }
    }
    __syncthreads();
    if (threadIdx.x < 128) {
      int b = g0 >> 8;              // 256 group-chunks per batch
      int s0i = (g0 & 255) * 4;
      size_t o = ((size_t)b * 128 + threadIdx.x) * 1024 + s0i;
      *(float4*)&mxbuf[o] = *(float4*)&tmx[threadIdx.x * 4];
      *(float4*)&mnbuf[o] = *(float4*)&tmn[threadIdx.x * 4];
    }
    __syncthreads();                // tiles reused next chunk
  }
  // stats tail (COUT=128)
#pragma unroll
  for (int t = 0; t < NT; t++) {
    s0[t] += __shfl_xor(s0[t], 16); s0[t] += __shfl_xor(s0[t], 32);
    s1[t] += __shfl_xor(s1[t], 16); s1[t] += __shfl_xor(s1[t], 32);
  }
  __shared__ float sp[4 * 2 * 128];
  if (quad == 0) {
#pragma unroll
    for (int t = 0; t < NT; t++) {
      sp[wv * 256 + l16 + 16 * t] = s0[t];
      sp[wv * 256 + 128 + l16 + 16 * t] = s1[t];
    }
  }
  __syncthreads();
  {
    int tt = threadIdx.x;           // 256 threads, 256 stat rows
    float p = sp[tt] + sp[256 + tt] + sp[512 + tt] + sp[768 + tt];
    partials[(size_t)tt * PNB + blockIdx.x] = p;
  }
}

// ---------------- epilogue: out1 = relu(s * (s>0 ? mx : mn) + h), coalesced ----------------
__global__ __launch_bounds__(256) void l3apply_kernel(
    const float* __restrict__ mnbuf, const float* __restrict__ mxbuf,
    const float* __restrict__ bn3, float* __restrict__ out1) {
  int i = blockIdx.x * 256 + threadIdx.x;   // 2,097,152 elements, layout [b][ch][s]
  int ch = (i >> 10) & 127;
  float s = bn3[ch], h = bn3[128 + ch];
  float v = (s > 0.f) ? mxbuf[i] : mnbuf[i];
  out1[i] = fmaxf(fmaf(v, s, h), 0.f);
}

extern "C" void kernel_launch(void* const* d_in, const int* in_sizes, int n_in,
                              void* d_out, int out_size, void* d_ws, size_t ws_size,
                              hipStream_t stream) {
  const float* xyz = (const float*)d_in[0];
  const float* pts = (const float*)d_in[1];
  const float* W1 = (const float*)d_in[2],  *b1 = (const float*)d_in[3];
  const float* g1 = (const float*)d_in[4],  *be1 = (const float*)d_in[5];
  const float* W2 = (const float*)d_in[6],  *b2 = (const float*)d_in[7];
  const float* g2 = (const float*)d_in[8],  *be2 = (const float*)d_in[9];
  const float* W3 = (const float*)d_in[10], *b3 = (const float*)d_in[11];
  const float* g3 = (const float*)d_in[12], *be3 = (const float*)d_in[13];
  float* out0 = (float*)d_out;                 // xyz_query_pc [16,3,1024]
  float* out1 = out0 + B_ * 3 * S_;            // new_points   [16,128,1024]

  char* ws = (char*)d_ws;
  float* new_xyz  = (float*)(ws);              // 49152 floats
  float* bn1      = (float*)(ws + 196608);     // 128
  float* bn2      = bn1 + 128;                 // 128
  float* bn3      = bn2 + 128;                 // 256
  int*   gidx     = (int*)(ws + 198656);       // 524288 ints
  float* partials = (float*)(ws + 2295808);    // 256*PNB floats (1 MB)
  unsigned short* y1 = (unsigned short*)(ws + 4392960);            // 64 MB bf16
  unsigned short* y2 = (unsigned short*)(ws + 4392960 + 67108864); // 64 MB bf16
  // mn/mx buffers reuse y1's space (y1 dead after layer2): 2 x 8 MB f32
  float* mnbuf = (float*)(ws + 4392960);
  float* mxbuf = (float*)(ws + 4392960 + 8388608);

  fps_kernel<<<B_, 512, 0, stream>>>(xyz, out0, new_xyz);
  ballq_kernel<<<4096, 256, 0, stream>>>(xyz, new_xyz, gidx);
  layer1_kernel<<<PNB, 256, 0, stream>>>(xyz, pts, new_xyz, gidx, W1, b1, y1, partials);
  finalize_kernel<<<64, 256, 0, stream>>>(partials, 64, g1, be1, bn1);
  mfma_layer_kernel<4, true><<<PNB, 256, 0, stream>>>(y1, W2, b2, bn1, y2, partials);
  finalize_kernel<<<64, 256, 0, stream>>>(partials, 64, g2, be2, bn2);
  l3fused_kernel<<<PNB, 256, 0, stream>>>(y2, W3, b3, bn2, mnbuf, mxbuf, partials);
  finalize_kernel<<<128, 256, 0, stream>>>(partials, 128, g3, be3, bn3);
  l3apply_kernel<<<8192, 256, 0, stream>>>(mnbuf, mxbuf, bn3, out1);
}